// Round 6
// baseline (862.454 us; speedup 1.0000x reference)
//
#include <hip/hip_runtime.h>
#include <hip/hip_bf16.h>

#define L_ 4
#define B_ 256
#define C_ 512
#define N_ 50000
#define K_ 20
#define NLIST 21
#define NCH 160       // n-chunks per l (chunk = 312/313 -> 5 tiles of 64, 2.4% waste)
#define BIGF 3.0e38f
#define BN 64         // bank cols per n-tile
#define KS 32         // K per step
#define NKS 16        // 512/32

// LDS byte offsets (per block)
#define QS0_O 0u       // 256 rows x 64B bf16
#define QS1_O 16384u
#define BS0_O 32768u   // 64 rows x 64B bf16
#define BS1_O 36864u
#define B2P_O 40960u   // 256 f32 partials
#define B2V_O 41984u   // 64 f32
#define SMEM_BYTES 42240
// sd (256 x 34 f32 = 34816B) aliases staging @0 after K-loop

typedef __attribute__((ext_vector_type(8))) short short8;
typedef __attribute__((ext_vector_type(4))) float f32x4;

__device__ __forceinline__ unsigned pk2(float lo, float hi) {
    __hip_bfloat162 h = __float22bfloat162_rn(make_float2(lo, hi));
    return *reinterpret_cast<unsigned*>(&h);
}
__device__ __forceinline__ float sq4(float4 v) {
    return v.x*v.x + v.y*v.y + v.z*v.z + v.w*v.w;
}

// ---------------- Phase 1: q (bf16) = mean_s feats ----------------
__global__ void qmean_kernel(const float* __restrict__ feats,
                             unsigned short* __restrict__ qbf)
{
    int gtid = blockIdx.x * 256 + threadIdx.x;
    int wid  = gtid >> 6;
    int lane = threadIdx.x & 63;
    const float4* src = reinterpret_cast<const float4*>(feats) + (size_t)wid * 64 + lane;
    float4 v = *src;
    float s = v.x + v.y + v.z + v.w;
    s += __shfl_xor(s, 1); s += __shfl_xor(s, 2);
    s += __shfl_xor(s, 4); s += __shfl_xor(s, 8);
    if ((lane & 15) == 0) {
        __hip_bfloat16 h = __float2bfloat16(s * (1.0f / 64.0f));
        qbf[wid * 4 + (lane >> 4)] = *reinterpret_cast<unsigned short*>(&h);
    }
}

// ---------------- Phase 2: BM=256 pipelined MFMA cross-GEMM + top-21 ----------------
__global__ __launch_bounds__(256, 3)
void dist_topk_kernel(const float* __restrict__ bank,
                      const unsigned short* __restrict__ qbf,
                      float* __restrict__ lists)
{
    __shared__ __align__(16) unsigned char smem[SMEM_BYTES];
    float* sd  = reinterpret_cast<float*>(smem);
    float* b2p = reinterpret_cast<float*>(smem + B2P_O);
    float* b2v = reinterpret_cast<float*>(smem + B2V_O);

    const int tid = threadIdx.x;
    const int l   = blockIdx.x / NCH;
    const int nc  = blockIdx.x - l * NCH;

    const unsigned short* qg = qbf + (size_t)l * B_ * C_;
    const float* bb = bank + (size_t)l * N_ * C_;
    const int n0 = (nc * 625) >> 1;          // nc*312.5
    const int n1 = ((nc + 1) * 625) >> 1;    // chunk size 312/313

    const int lane = tid & 63;
    const int wid  = tid >> 6;               // wave owns q-rows 64*wid..+63
    const int c_lo = lane & 15;
    const int r_hi = lane >> 4;

    // Q staging: slot i = tid+256j -> row=i>>2, phys 16B-slot=i&3;
    // LDS[row][p] holds logical k-slot p^swz(row), swz(row)=(row>>1)&3
    int q_src[4]; unsigned q_dst[4];
#pragma unroll
    for (int j = 0; j < 4; ++j) {
        const int i = tid + 256*j, row = i >> 2, slot = i & 3;
        q_src[j] = row * C_ + (slot << 3);                                // linear global (elems)
        q_dst[j] = (unsigned)(row * 64 + ((slot ^ ((row >> 1) & 3)) << 4)); // swizzled LDS bytes
    }
    // B staging: thread -> row=tid>>2, seg=tid&3 (8 f32)
    const int brow  = tid >> 2;
    const int bsegk = (tid & 3) << 3;
    const unsigned b_dst = (unsigned)(brow * 64 + (((tid & 3) ^ ((brow >> 1) & 3)) << 4));

    // fragment read offsets (swizzle-matched): logical k-slot r_hi
    unsigned offA[4], offB[4];
#pragma unroll
    for (int m = 0; m < 4; ++m) {
        const int row = wid*64 + m*16 + c_lo;
        offA[m] = (unsigned)(row*64 + ((r_hi ^ ((row >> 1) & 3)) << 4));
    }
#pragma unroll
    for (int n = 0; n < 4; ++n) {
        const int row = n*16 + c_lo;
        offB[n] = (unsigned)(row*64 + ((r_hi ^ ((row >> 1) & 3)) << 4));
    }

    float list[NLIST];
#pragma unroll
    for (int i = 0; i < NLIST; ++i) list[i] = BIGF;

#pragma unroll 1
    for (int nt = n0; nt < n1; nt += BN) {
        f32x4 acc[4][4];
#pragma unroll
        for (int m = 0; m < 4; ++m)
#pragma unroll
            for (int n = 0; n < 4; ++n) acc[m][n] = (f32x4){0.f, 0.f, 0.f, 0.f};
        float b2a = 0.f;

        // ---- prologue: stage K-step 0 into buffer 0 ----
        {
            short8 qv[4];
#pragma unroll
            for (int j = 0; j < 4; ++j)
                qv[j] = *reinterpret_cast<const short8*>(qg + q_src[j]);
            const int gr = nt + brow;
            float4 f0 = make_float4(0.f,0.f,0.f,0.f), f1 = f0;
            if (gr < n1) {
                const float* s = bb + (size_t)gr * C_ + bsegk;
                f0 = *reinterpret_cast<const float4*>(s);
                f1 = *reinterpret_cast<const float4*>(s + 4);
            }
            b2a += sq4(f0) + sq4(f1);
#pragma unroll
            for (int j = 0; j < 4; ++j)
                *reinterpret_cast<short8*>(smem + QS0_O + q_dst[j]) = qv[j];
            union { short8 s; unsigned u[4]; } pk;
            pk.u[0] = pk2(f0.x,f0.y); pk.u[1] = pk2(f0.z,f0.w);
            pk.u[2] = pk2(f1.x,f1.y); pk.u[3] = pk2(f1.z,f1.w);
            *reinterpret_cast<short8*>(smem + BS0_O + b_dst) = pk.s;
        }
        __syncthreads();

        // ---- K loop: 1 barrier/step; t+1 loads issued before MFMA(t) ----
#pragma unroll 2
        for (int ks = 0; ks < NKS; ++ks) {
            const unsigned qsrc = (ks & 1) ? QS1_O : QS0_O;
            const unsigned bsrc = (ks & 1) ? BS1_O : BS0_O;
            const bool have = (ks + 1) < NKS;

            short8 qv[4];
            float4 f0 = make_float4(0.f,0.f,0.f,0.f), f1 = f0;
            if (have) {
                const int kb = (ks + 1) * KS;
#pragma unroll
                for (int j = 0; j < 4; ++j)
                    qv[j] = *reinterpret_cast<const short8*>(qg + q_src[j] + kb);
                const int gr = nt + brow;
                if (gr < n1) {
                    const float* s = bb + (size_t)gr * C_ + kb + bsegk;
                    f0 = *reinterpret_cast<const float4*>(s);
                    f1 = *reinterpret_cast<const float4*>(s + 4);
                }
            }

            short8 a[4];
#pragma unroll
            for (int m = 0; m < 4; ++m)
                a[m] = *reinterpret_cast<const short8*>(smem + qsrc + offA[m]);
#pragma unroll
            for (int n = 0; n < 4; ++n) {
                const short8 bn = *reinterpret_cast<const short8*>(smem + bsrc + offB[n]);
#pragma unroll
                for (int m = 0; m < 4; ++m)
                    acc[m][n] = __builtin_amdgcn_mfma_f32_16x16x32_bf16(a[m], bn, acc[m][n], 0, 0, 0);
            }

            if (have) {
                b2a += sq4(f0) + sq4(f1);
                const unsigned qd = (ks & 1) ? QS0_O : QS1_O;
                const unsigned bd = (ks & 1) ? BS0_O : BS1_O;
#pragma unroll
                for (int j = 0; j < 4; ++j)
                    *reinterpret_cast<short8*>(smem + qd + q_dst[j]) = qv[j];
                union { short8 s; unsigned u[4]; } pk;
                pk.u[0] = pk2(f0.x,f0.y); pk.u[1] = pk2(f0.z,f0.w);
                pk.u[2] = pk2(f1.x,f1.y); pk.u[3] = pk2(f1.z,f1.w);
                *reinterpret_cast<short8*>(smem + bd + b_dst) = pk.s;
            }
            __syncthreads();
        }

        // ---- deterministic b2 reduction: b2p[row*4+seg] -> b2v[row] ----
        b2p[tid] = b2a;
        __syncthreads();
        if (tid < 64) {
            const float* p = b2p + tid*4;
            b2v[tid] = (p[0] + p[1]) + (p[2] + p[3]);
        }
        __syncthreads();

        // ---- dump + scan, two 32-col phases (sd[256][34] aliases staging) ----
#pragma unroll 1
        for (int ph = 0; ph < 2; ++ph) {
            // C/D layout: col = lane&15, row = (lane>>4)*4 + reg
#pragma unroll
            for (int m = 0; m < 4; ++m)
#pragma unroll
                for (int nn = 0; nn < 2; ++nn) {
                    const int n    = 2*ph + nn;
                    const int col  = 16*n + c_lo;
                    const int lcol = 16*nn + c_lo;
                    const float bv = b2v[col];
                    const bool ok  = (nt + col) < n1;
#pragma unroll
                    for (int rg = 0; rg < 4; ++rg) {
                        const int row = wid*64 + m*16 + r_hi*4 + rg;
                        const float v = fmaf(-2.0f, acc[m][n][rg], bv);
                        sd[row*34 + lcol] = ok ? v : BIGF;
                    }
                }
            __syncthreads();
            // scan: thread == row, 32 cols, batch-4 prefilter
            {
                const float* srow = sd + tid*34;
#pragma unroll
                for (int bt = 0; bt < 8; ++bt) {
                    const float2 u = *reinterpret_cast<const float2*>(srow + (bt << 2));
                    const float2 w = *reinterpret_cast<const float2*>(srow + (bt << 2) + 2);
                    const float m4 = fminf(fminf(u.x, u.y), fminf(w.x, w.y));
                    if (m4 < list[NLIST-1]) {
                        float cand[4] = {u.x, u.y, w.x, w.y};
#pragma unroll
                        for (int c4 = 0; c4 < 4; ++c4) {
                            float v = cand[c4];
                            if (v < list[NLIST-1]) {
#pragma unroll
                                for (int i = 0; i < NLIST; ++i) {
                                    const float lo = fminf(list[i], v);
                                    const float hi = fmaxf(list[i], v);
                                    list[i] = lo; v = hi;
                                }
                            }
                        }
                    }
                }
            }
            __syncthreads();
        }
    }

    // ---- one thread per row: list is already the row's sorted top-21 ----
    {
        float* outp = lists + ((size_t)(l*B_ + tid)*NCH + nc)*NLIST;
#pragma unroll
        for (int i = 0; i < NLIST; ++i) outp[i] = list[i];
    }
}

// ---------------- Phase 3: merge 160 sorted chunk-lists per (l,b), LID ----------------
__global__ void lid_kernel(const float* __restrict__ lists,
                           const unsigned short* __restrict__ qbf,
                           float* __restrict__ out)
{
    __shared__ float pops[4][NLIST];
    const int lane = threadIdx.x & 63;
    const int w    = threadIdx.x >> 6;
    const int gw   = blockIdx.x * 4 + w;   // 0..1023 = (l,b)
    const int l    = gw & 3;
    const int b    = gw >> 2;

    const unsigned short* qr = qbf + ((size_t)l*B_ + b)*C_;
    short8 qv = *reinterpret_cast<const short8*>(qr + lane*8);
    float q2 = 0.f;
#pragma unroll
    for (int i = 0; i < 8; ++i) {
        unsigned u = ((unsigned)(unsigned short)qv[i]) << 16;
        float f = __uint_as_float(u);
        q2 += f*f;
    }
    q2 += __shfl_xor(q2,1); q2 += __shfl_xor(q2,2); q2 += __shfl_xor(q2,4);
    q2 += __shfl_xor(q2,8); q2 += __shfl_xor(q2,16); q2 += __shfl_xor(q2,32);

    // 160 lists: lane owns chunks {lane, lane+64, lane+128(lane<32)}
    const float* base = lists + (size_t)(l*B_ + b) * NCH * NLIST;
    int p0 = 0, p1 = 0, p2 = 0;
#pragma unroll 1
    for (int i = 0; i < NLIST; ++i) {
        const float h0 = (p0 < NLIST) ? base[(size_t)lane*NLIST + p0] : BIGF;
        const float h1 = (p1 < NLIST) ? base[(size_t)(lane+64)*NLIST + p1] : BIGF;
        const float h2 = (lane < 32 && p2 < NLIST) ? base[(size_t)(lane+128)*NLIST + p2] : BIGF;
        const float h  = fminf(h0, fminf(h1, h2));
        float m = h;
        m = fminf(m, __shfl_xor(m,1));  m = fminf(m, __shfl_xor(m,2));
        m = fminf(m, __shfl_xor(m,4));  m = fminf(m, __shfl_xor(m,8));
        m = fminf(m, __shfl_xor(m,16)); m = fminf(m, __shfl_xor(m,32));
        const unsigned long long ball = __ballot(h == m);
        if (lane == __ffsll(ball) - 1) {
            if (h0 == m)      ++p0;
            else if (h1 == m) ++p1;
            else              ++p2;
        }
        if (lane == 0) pops[w][i] = fmaxf(q2 + m, 0.f);
    }
    __syncthreads();

    const float r2 = pops[w][NLIST-1];
    float t = 0.f;
    if (lane >= 1 && lane < NLIST) t = 0.5f * logf(pops[w][lane] / r2);
    t += __shfl_xor(t,1); t += __shfl_xor(t,2); t += __shfl_xor(t,4);
    t += __shfl_xor(t,8); t += __shfl_xor(t,16); t += __shfl_xor(t,32);

    if (lane == 0) out[(size_t)b * L_ + l] = -(float)K_ / t;
}

extern "C" void kernel_launch(void* const* d_in, const int* in_sizes, int n_in,
                              void* d_out, int out_size, void* d_ws, size_t ws_size,
                              hipStream_t stream)
{
    (void)in_sizes; (void)n_in; (void)out_size; (void)ws_size;
    const float* feats = (const float*)d_in[0];
    const float* bank  = (const float*)d_in[1];
    unsigned short* qbf = (unsigned short*)d_ws;                 // 1 MiB bf16 q
    float* lists = (float*)((char*)d_ws + (size_t)L_*B_*C_*2);   // 1024*160*21*4 = 13.8 MiB

    qmean_kernel<<<32768, 256, 0, stream>>>(feats, qbf);
    dist_topk_kernel<<<L_*NCH, 256, 0, stream>>>(bank, qbf, lists);
    lid_kernel<<<256, 256, 0, stream>>>(lists, qbf, (float*)d_out);
}

// Round 7
// 242.641 us; speedup vs baseline: 3.5544x; 3.5544x over previous
//
#include <hip/hip_runtime.h>
#include <hip/hip_bf16.h>

#define L_ 4
#define B_ 256
#define C_ 512
#define N_ 50000
#define K_ 20
#define NLIST 21
#define NCH 160       // n-chunks per l (chunk = 312/313 -> 5 tiles of 64, 2.4% waste)
#define BIGF 3.0e38f
#define BN 64         // bank cols per n-tile
#define KS 32         // K per step
#define NKS 16        // 512/32

// LDS byte offsets (per block)
#define QS0_O 0u       // 256 rows x 64B bf16
#define QS1_O 16384u
#define BS0_O 32768u   // 64 rows x 64B bf16
#define BS1_O 36864u
#define B2P_O 40960u   // 256 f32 partials
#define B2V_O 41984u   // 64 f32
#define SMEM_BYTES 42240
// sd (256 x 34 f32 = 34816B) aliases staging @0 after K-loop

typedef __attribute__((ext_vector_type(8))) short short8;
typedef __attribute__((ext_vector_type(4))) float f32x4;

__device__ __forceinline__ unsigned pk2(float lo, float hi) {
    __hip_bfloat162 h = __float22bfloat162_rn(make_float2(lo, hi));
    return *reinterpret_cast<unsigned*>(&h);
}
__device__ __forceinline__ float sq4(float4 v) {
    return v.x*v.x + v.y*v.y + v.z*v.z + v.w*v.w;
}

// ---------------- Phase 1: q (bf16) = mean_s feats ----------------
__global__ void qmean_kernel(const float* __restrict__ feats,
                             unsigned short* __restrict__ qbf)
{
    int gtid = blockIdx.x * 256 + threadIdx.x;
    int wid  = gtid >> 6;
    int lane = threadIdx.x & 63;
    const float4* src = reinterpret_cast<const float4*>(feats) + (size_t)wid * 64 + lane;
    float4 v = *src;
    float s = v.x + v.y + v.z + v.w;
    s += __shfl_xor(s, 1); s += __shfl_xor(s, 2);
    s += __shfl_xor(s, 4); s += __shfl_xor(s, 8);
    if ((lane & 15) == 0) {
        __hip_bfloat16 h = __float2bfloat16(s * (1.0f / 64.0f));
        qbf[wid * 4 + (lane >> 4)] = *reinterpret_cast<unsigned short*>(&h);
    }
}

// ---------------- Phase 2: BM=256 pipelined MFMA cross-GEMM + top-21 ----------------
__global__ __launch_bounds__(256, 3)
void dist_topk_kernel(const float* __restrict__ bank,
                      const unsigned short* __restrict__ qbf,
                      float* __restrict__ lists)
{
    __shared__ __align__(16) unsigned char smem[SMEM_BYTES];
    float* sd  = reinterpret_cast<float*>(smem);
    float* b2p = reinterpret_cast<float*>(smem + B2P_O);
    float* b2v = reinterpret_cast<float*>(smem + B2V_O);

    const int tid = threadIdx.x;
    const int l   = blockIdx.x / NCH;
    const int nc  = blockIdx.x - l * NCH;

    const unsigned short* qg = qbf + (size_t)l * B_ * C_;
    const float* bb = bank + (size_t)l * N_ * C_;
    const int n0 = (nc * 625) >> 1;          // nc*312.5
    const int n1 = ((nc + 1) * 625) >> 1;    // chunk size 312/313

    const int lane = tid & 63;
    const int wid  = tid >> 6;               // wave owns q-rows 64*wid..+63
    const int c_lo = lane & 15;
    const int r_hi = lane >> 4;

    // Q staging: slot i = tid+256j -> row=i>>2, phys 16B-slot=i&3;
    // LDS[row][p] holds logical k-slot p^swz(row), swz(row)=(row>>1)&3
    int q_src[4]; unsigned q_dst[4];
#pragma unroll
    for (int j = 0; j < 4; ++j) {
        const int i = tid + 256*j, row = i >> 2, slot = i & 3;
        q_src[j] = row * C_ + (slot << 3);                                // linear global (elems)
        q_dst[j] = (unsigned)(row * 64 + ((slot ^ ((row >> 1) & 3)) << 4)); // swizzled LDS bytes
    }
    // B staging: thread -> row=tid>>2, seg=tid&3 (8 f32)
    const int brow  = tid >> 2;
    const int bsegk = (tid & 3) << 3;
    const unsigned b_dst = (unsigned)(brow * 64 + (((tid & 3) ^ ((brow >> 1) & 3)) << 4));

    // fragment read offsets (swizzle-matched): logical k-slot r_hi
    unsigned offA[4], offB[4];
#pragma unroll
    for (int m = 0; m < 4; ++m) {
        const int row = wid*64 + m*16 + c_lo;
        offA[m] = (unsigned)(row*64 + ((r_hi ^ ((row >> 1) & 3)) << 4));
    }
#pragma unroll
    for (int n = 0; n < 4; ++n) {
        const int row = n*16 + c_lo;
        offB[n] = (unsigned)(row*64 + ((r_hi ^ ((row >> 1) & 3)) << 4));
    }

    float list[NLIST];
#pragma unroll
    for (int i = 0; i < NLIST; ++i) list[i] = BIGF;

#pragma unroll 1
    for (int nt = n0; nt < n1; nt += BN) {
        f32x4 acc[4][4];
#pragma unroll
        for (int m = 0; m < 4; ++m)
#pragma unroll
            for (int n = 0; n < 4; ++n) acc[m][n] = (f32x4){0.f, 0.f, 0.f, 0.f};
        float b2a = 0.f;

        // ---- prologue: stage K-step 0 into buffer 0 ----
        {
            short8 qv[4];
#pragma unroll
            for (int j = 0; j < 4; ++j)
                qv[j] = *reinterpret_cast<const short8*>(qg + q_src[j]);
            const int gr = nt + brow;
            float4 f0 = make_float4(0.f,0.f,0.f,0.f), f1 = f0;
            if (gr < n1) {
                const float* s = bb + (size_t)gr * C_ + bsegk;
                f0 = *reinterpret_cast<const float4*>(s);
                f1 = *reinterpret_cast<const float4*>(s + 4);
            }
            b2a += sq4(f0) + sq4(f1);
#pragma unroll
            for (int j = 0; j < 4; ++j)
                *reinterpret_cast<short8*>(smem + QS0_O + q_dst[j]) = qv[j];
            union { short8 s; unsigned u[4]; } pk;
            pk.u[0] = pk2(f0.x,f0.y); pk.u[1] = pk2(f0.z,f0.w);
            pk.u[2] = pk2(f1.x,f1.y); pk.u[3] = pk2(f1.z,f1.w);
            *reinterpret_cast<short8*>(smem + BS0_O + b_dst) = pk.s;
        }
        __syncthreads();

        // ---- K loop: 1 barrier/step; t+1 loads issued before MFMA(t) ----
#pragma unroll 2
        for (int ks = 0; ks < NKS; ++ks) {
            const unsigned qsrc = (ks & 1) ? QS1_O : QS0_O;
            const unsigned bsrc = (ks & 1) ? BS1_O : BS0_O;
            const bool have = (ks + 1) < NKS;

            short8 qv[4];
            float4 f0 = make_float4(0.f,0.f,0.f,0.f), f1 = f0;
            if (have) {
                const int kb = (ks + 1) * KS;
#pragma unroll
                for (int j = 0; j < 4; ++j)
                    qv[j] = *reinterpret_cast<const short8*>(qg + q_src[j] + kb);
                const int gr = nt + brow;
                if (gr < n1) {
                    const float* s = bb + (size_t)gr * C_ + kb + bsegk;
                    f0 = *reinterpret_cast<const float4*>(s);
                    f1 = *reinterpret_cast<const float4*>(s + 4);
                }
            }

            short8 a[4];
#pragma unroll
            for (int m = 0; m < 4; ++m)
                a[m] = *reinterpret_cast<const short8*>(smem + qsrc + offA[m]);
#pragma unroll
            for (int n = 0; n < 4; ++n) {
                const short8 bn = *reinterpret_cast<const short8*>(smem + bsrc + offB[n]);
#pragma unroll
                for (int m = 0; m < 4; ++m)
                    acc[m][n] = __builtin_amdgcn_mfma_f32_16x16x32_bf16(a[m], bn, acc[m][n], 0, 0, 0);
            }

            if (have) {
                b2a += sq4(f0) + sq4(f1);
                const unsigned qd = (ks & 1) ? QS0_O : QS1_O;
                const unsigned bd = (ks & 1) ? BS0_O : BS1_O;
#pragma unroll
                for (int j = 0; j < 4; ++j)
                    *reinterpret_cast<short8*>(smem + qd + q_dst[j]) = qv[j];
                union { short8 s; unsigned u[4]; } pk;
                pk.u[0] = pk2(f0.x,f0.y); pk.u[1] = pk2(f0.z,f0.w);
                pk.u[2] = pk2(f1.x,f1.y); pk.u[3] = pk2(f1.z,f1.w);
                *reinterpret_cast<short8*>(smem + bd + b_dst) = pk.s;
            }
            __syncthreads();
        }

        // ---- deterministic b2 reduction: b2p[row*4+seg] -> b2v[row] ----
        b2p[tid] = b2a;
        __syncthreads();
        if (tid < 64) {
            const float* p = b2p + tid*4;
            b2v[tid] = (p[0] + p[1]) + (p[2] + p[3]);
        }
        __syncthreads();

        // ---- dump + scan, two 32-col phases. FULLY UNROLLED so `ph` is a
        // compile-time constant and acc[m][2*ph+nn] stays register-indexed
        // (rule #20: runtime-indexed ext_vector arrays go to scratch).
#pragma unroll
        for (int ph = 0; ph < 2; ++ph) {
            // C/D layout: col = lane&15, row = (lane>>4)*4 + reg
#pragma unroll
            for (int m = 0; m < 4; ++m)
#pragma unroll
                for (int nn = 0; nn < 2; ++nn) {
                    const int n    = 2*ph + nn;
                    const int col  = 16*n + c_lo;
                    const int lcol = 16*nn + c_lo;
                    const float bv = b2v[col];
                    const bool ok  = (nt + col) < n1;
#pragma unroll
                    for (int rg = 0; rg < 4; ++rg) {
                        const int row = wid*64 + m*16 + r_hi*4 + rg;
                        const float v = fmaf(-2.0f, acc[m][n][rg], bv);
                        sd[row*34 + lcol] = ok ? v : BIGF;
                    }
                }
            __syncthreads();
            // scan: thread == row, 32 cols, batch-4 prefilter
            {
                const float* srow = sd + tid*34;
#pragma unroll
                for (int bt = 0; bt < 8; ++bt) {
                    const float2 u = *reinterpret_cast<const float2*>(srow + (bt << 2));
                    const float2 w = *reinterpret_cast<const float2*>(srow + (bt << 2) + 2);
                    const float m4 = fminf(fminf(u.x, u.y), fminf(w.x, w.y));
                    if (m4 < list[NLIST-1]) {
                        float cand[4] = {u.x, u.y, w.x, w.y};
#pragma unroll
                        for (int c4 = 0; c4 < 4; ++c4) {
                            float v = cand[c4];
                            if (v < list[NLIST-1]) {
#pragma unroll
                                for (int i = 0; i < NLIST; ++i) {
                                    const float lo = fminf(list[i], v);
                                    const float hi = fmaxf(list[i], v);
                                    list[i] = lo; v = hi;
                                }
                            }
                        }
                    }
                }
            }
            __syncthreads();
        }
    }

    // ---- one thread per row: list is already the row's sorted top-21 ----
    {
        float* outp = lists + ((size_t)(l*B_ + tid)*NCH + nc)*NLIST;
#pragma unroll
        for (int i = 0; i < NLIST; ++i) outp[i] = list[i];
    }
}

// ---------------- Phase 3: merge 160 sorted chunk-lists per (l,b), LID ----------------
__global__ void lid_kernel(const float* __restrict__ lists,
                           const unsigned short* __restrict__ qbf,
                           float* __restrict__ out)
{
    __shared__ float pops[4][NLIST];
    const int lane = threadIdx.x & 63;
    const int w    = threadIdx.x >> 6;
    const int gw   = blockIdx.x * 4 + w;   // 0..1023 = (l,b)
    const int l    = gw & 3;
    const int b    = gw >> 2;

    const unsigned short* qr = qbf + ((size_t)l*B_ + b)*C_;
    short8 qv = *reinterpret_cast<const short8*>(qr + lane*8);
    float q2 = 0.f;
#pragma unroll
    for (int i = 0; i < 8; ++i) {
        unsigned u = ((unsigned)(unsigned short)qv[i]) << 16;
        float f = __uint_as_float(u);
        q2 += f*f;
    }
    q2 += __shfl_xor(q2,1); q2 += __shfl_xor(q2,2); q2 += __shfl_xor(q2,4);
    q2 += __shfl_xor(q2,8); q2 += __shfl_xor(q2,16); q2 += __shfl_xor(q2,32);

    // 160 lists: lane owns chunks {lane, lane+64, lane+128(lane<32)}
    const float* base = lists + (size_t)(l*B_ + b) * NCH * NLIST;
    int p0 = 0, p1 = 0, p2 = 0;
#pragma unroll 1
    for (int i = 0; i < NLIST; ++i) {
        const float h0 = (p0 < NLIST) ? base[(size_t)lane*NLIST + p0] : BIGF;
        const float h1 = (p1 < NLIST) ? base[(size_t)(lane+64)*NLIST + p1] : BIGF;
        const float h2 = (lane < 32 && p2 < NLIST) ? base[(size_t)(lane+128)*NLIST + p2] : BIGF;
        const float h  = fminf(h0, fminf(h1, h2));
        float m = h;
        m = fminf(m, __shfl_xor(m,1));  m = fminf(m, __shfl_xor(m,2));
        m = fminf(m, __shfl_xor(m,4));  m = fminf(m, __shfl_xor(m,8));
        m = fminf(m, __shfl_xor(m,16)); m = fminf(m, __shfl_xor(m,32));
        const unsigned long long ball = __ballot(h == m);
        if (lane == __ffsll(ball) - 1) {
            if (h0 == m)      ++p0;
            else if (h1 == m) ++p1;
            else              ++p2;
        }
        if (lane == 0) pops[w][i] = fmaxf(q2 + m, 0.f);
    }
    __syncthreads();

    const float r2 = pops[w][NLIST-1];
    float t = 0.f;
    if (lane >= 1 && lane < NLIST) t = 0.5f * logf(pops[w][lane] / r2);
    t += __shfl_xor(t,1); t += __shfl_xor(t,2); t += __shfl_xor(t,4);
    t += __shfl_xor(t,8); t += __shfl_xor(t,16); t += __shfl_xor(t,32);

    if (lane == 0) out[(size_t)b * L_ + l] = -(float)K_ / t;
}

extern "C" void kernel_launch(void* const* d_in, const int* in_sizes, int n_in,
                              void* d_out, int out_size, void* d_ws, size_t ws_size,
                              hipStream_t stream)
{
    (void)in_sizes; (void)n_in; (void)out_size; (void)ws_size;
    const float* feats = (const float*)d_in[0];
    const float* bank  = (const float*)d_in[1];
    unsigned short* qbf = (unsigned short*)d_ws;                 // 1 MiB bf16 q
    float* lists = (float*)((char*)d_ws + (size_t)L_*B_*C_*2);   // 1024*160*21*4 = 13.8 MiB

    qmean_kernel<<<32768, 256, 0, stream>>>(feats, qbf);
    dist_topk_kernel<<<L_*NCH, 256, 0, stream>>>(bank, qbf, lists);
    lid_kernel<<<256, 256, 0, stream>>>(lists, qbf, (float*)d_out);
}